// Round 3
// baseline (5360.410 us; speedup 1.0000x reference)
//
#include <hip/hip_runtime.h>
#include <hip/hip_fp16.h>
#include <math.h>

#define BATCH 128
#define NDIM 512
#define NPAIR 256          // row-pairs per batch
#define POWER_ITERS 30
#define N_ITERS 500

// per-thread partition of its 64 owned row-pairs:
#define REGP 48            // pairs held in VGPRs (192 VGPRs)
#define LDSP 6             // pairs held in LDS (48 KB/block)
#define STRP 10            // pairs streamed from L2 each matvec (80 KB/block/iter)

typedef _Float16 half2_t __attribute__((ext_vector_type(2)));

union H2x4 { float4 f4; half2_t h[4]; };

// ---------------- helpers ----------------
__device__ __forceinline__ float4 ld4(const float* p) { return *(const float4*)p; }
__device__ __forceinline__ float4 f4_add(float4 a, float4 b) {
  return make_float4(a.x + b.x, a.y + b.y, a.z + b.z, a.w + b.w);
}
__device__ __forceinline__ float wave_sum64(float x) {
#pragma unroll
  for (int off = 1; off < 64; off <<= 1) x += __shfl_xor(x, off, 64);
  return x;
}
__device__ __forceinline__ float wave_max64(float x) {
#pragma unroll
  for (int off = 1; off < 64; off <<= 1) x = fmaxf(x, __shfl_xor(x, off, 64));
  return x;
}

// ---- conversion: Sh[b][pair][col] = half2( sym(2p,col), sym(2p+1,col) ) ----
__global__ void sym_conv_kernel(const float* __restrict__ S, half2_t* __restrict__ Sh) {
  const int bb = blockIdx.x, ti = blockIdx.y, tj = blockIdx.z;
  if (tj < ti) return;
  __shared__ float ta[32][33];
  __shared__ float tb[32][33];
  const float* base = S + (size_t)bb * NDIM * NDIM;
  half2_t* dst = Sh + (size_t)bb * NPAIR * NDIM;
  const int tx = threadIdx.x, ty = threadIdx.y;  // 32 x 8
#pragma unroll
  for (int k = 0; k < 4; k++) {
    int r = ty + 8 * k;
    ta[r][tx] = base[(size_t)(ti * 32 + r) * NDIM + tj * 32 + tx];
    tb[r][tx] = base[(size_t)(tj * 32 + r) * NDIM + ti * 32 + tx];
  }
  __syncthreads();
#pragma unroll
  for (int k = 0; k < 2; k++) {
    int pi = ty + 8 * k;  // local pair 0..15
    float v0 = 0.5f * (ta[2 * pi][tx] + tb[tx][2 * pi]);
    float v1 = 0.5f * (ta[2 * pi + 1][tx] + tb[tx][2 * pi + 1]);
    half2_t o; o[0] = (_Float16)v0; o[1] = (_Float16)v1;
    dst[(size_t)(ti * 16 + pi) * NDIM + tj * 32 + tx] = o;
  }
  if (ti != tj) {
#pragma unroll
    for (int k = 0; k < 2; k++) {
      int pi = ty + 8 * k;
      float v0 = 0.5f * (tb[2 * pi][tx] + ta[tx][2 * pi]);
      float v1 = 0.5f * (tb[2 * pi + 1][tx] + ta[tx][2 * pi + 1]);
      half2_t o; o[0] = (_Float16)v0; o[1] = (_Float16)v1;
      dst[(size_t)(tj * 16 + pi) * NDIM + ti * 32 + tx] = o;
    }
  }
}

// ---- matvec partial over this thread's 64 pairs: regs + LDS + L2 stream ----
__device__ __forceinline__ float4 matvec3(const float4 (&sregq)[REGP],
                                          const float4 (*ldsSg)[128],
                                          const half2_t* __restrict__ Sb,
                                          const half2_t* __restrict__ yb,
                                          int g, int c) {
  // issue streamed loads first so L2 latency overlaps the register FMAs
  float4 st[STRP];
  {
    const half2_t* gp = Sb + (size_t)(64 * g + REGP + LDSP) * NDIM + 4 * c;
#pragma unroll
    for (int p = 0; p < STRP; p++) st[p] = *(const float4*)(gp + (size_t)p * NDIM);
  }
  // two accumulator sets to halve the fdot2 dependency chain
  float a[2][4] = {{0, 0, 0, 0}, {0, 0, 0, 0}};
  // register part: pairs [0, REGP)
#pragma unroll
  for (int ch = 0; ch < REGP / 4; ch++) {
    H2x4 y4; y4.f4 = *(const float4*)(yb + 4 * ch);  // wave-uniform LDS broadcast
    float* ac = a[ch & 1];
#pragma unroll
    for (int q = 0; q < 4; q++) {
      H2x4 u; u.f4 = sregq[4 * ch + q];
      half2_t yy = y4.h[q];
      ac[0] = __builtin_amdgcn_fdot2(u.h[0], yy, ac[0], false);
      ac[1] = __builtin_amdgcn_fdot2(u.h[1], yy, ac[1], false);
      ac[2] = __builtin_amdgcn_fdot2(u.h[2], yy, ac[2], false);
      ac[3] = __builtin_amdgcn_fdot2(u.h[3], yy, ac[3], false);
    }
  }
  // LDS part: pairs [REGP, REGP+LDSP)
#pragma unroll
  for (int p = 0; p < LDSP; p++) {
    H2x4 u; u.f4 = ldsSg[p][c];
    half2_t yy = yb[REGP + p];
    float* ac = a[p & 1];
    ac[0] = __builtin_amdgcn_fdot2(u.h[0], yy, ac[0], false);
    ac[1] = __builtin_amdgcn_fdot2(u.h[1], yy, ac[1], false);
    ac[2] = __builtin_amdgcn_fdot2(u.h[2], yy, ac[2], false);
    ac[3] = __builtin_amdgcn_fdot2(u.h[3], yy, ac[3], false);
  }
  // streamed part: pairs [REGP+LDSP, 64)
#pragma unroll
  for (int p = 0; p < STRP; p++) {
    H2x4 u; u.f4 = st[p];
    half2_t yy = yb[REGP + LDSP + p];
    float* ac = a[p & 1];
    ac[0] = __builtin_amdgcn_fdot2(u.h[0], yy, ac[0], false);
    ac[1] = __builtin_amdgcn_fdot2(u.h[1], yy, ac[1], false);
    ac[2] = __builtin_amdgcn_fdot2(u.h[2], yy, ac[2], false);
    ac[3] = __builtin_amdgcn_fdot2(u.h[3], yy, ac[3], false);
  }
  return make_float4(a[0][0] + a[1][0], a[0][1] + a[1][1],
                     a[0][2] + a[1][2], a[0][3] + a[1][3]);
}

__device__ __forceinline__ void combine_z(const float* __restrict__ zsc, int lane, float* z8) {
#pragma unroll
  for (int q = 0; q < 2; q++) {
    float4 zz = ld4(zsc + 0 * NDIM + 8 * lane + 4 * q);
    zz = f4_add(zz, ld4(zsc + 1 * NDIM + 8 * lane + 4 * q));
    zz = f4_add(zz, ld4(zsc + 2 * NDIM + 8 * lane + 4 * q));
    zz = f4_add(zz, ld4(zsc + 3 * NDIM + 8 * lane + 4 * q));
    z8[4 * q + 0] = zz.x; z8[4 * q + 1] = zz.y;
    z8[4 * q + 2] = zz.z; z8[4 * q + 3] = zz.w;
  }
}

__device__ __forceinline__ void store_y_pairs(half2_t* ysh, int lane, const float* y8) {
  H2x4 yo;
#pragma unroll
  for (int q = 0; q < 4; q++) {
    half2_t v; v[0] = (_Float16)y8[2 * q]; v[1] = (_Float16)y8[2 * q + 1];
    yo.h[q] = v;
  }
  *(float4*)(ysh + 4 * lane) = yo.f4;
}

__global__ __attribute__((amdgpu_waves_per_eu(2, 2))) void __launch_bounds__(512)
qp_solver_h(const float* __restrict__ mu,
            const half2_t* __restrict__ Sh,
            float* __restrict__ out) {
  __shared__ half2_t yh2[NPAIR];            // 1 KB: y as fp16 row-pairs
  __shared__ float zsc[4 * NDIM];           // 8 KB: per-group matvec partials
  __shared__ float4 ldsS[4][LDSP][128];     // 48 KB: LDS-resident slab of S
  __shared__ int stopf;
  const int tid = threadIdx.x;
  const int g = tid >> 7;
  const int c = tid & 127;
  const int b = blockIdx.x;
  const half2_t* Sb = Sh + (size_t)b * NPAIR * NDIM;
  const half2_t* yb = yh2 + 64 * g;
  const float invn = 1.0f / (float)NDIM;

  // ---- stage: registers (pinned) + LDS slab ----
  float4 sregq[REGP];
  {
    const half2_t* rp = Sb + (size_t)(64 * g) * NDIM + 4 * c;
#pragma unroll
    for (int p = 0; p < REGP; p++)
      sregq[p] = *(const float4*)(rp + (size_t)p * NDIM);
#pragma unroll
    for (int p = 0; p < LDSP; p++)
      ldsS[g][p][c] = *(const float4*)(rp + (size_t)(REGP + p) * NDIM);
  }
  // pin: make values opaque so LLVM can't spill-as-cold or re-load from global
#pragma unroll
  for (int p = 0; p < REGP; p++) {
    asm volatile("" : "+v"(sregq[p].x), "+v"(sregq[p].y),
                      "+v"(sregq[p].z), "+v"(sregq[p].w));
  }

  if (tid < NPAIR) { half2_t v; v[0] = (_Float16)invn; v[1] = (_Float16)invn; yh2[tid] = v; }
  if (tid == 0) stopf = 0;
  __syncthreads();

  float y8[8];  // wave0 only: current vector fp32
  // ---- power iteration ----
  for (int it = 0; it < POWER_ITERS; it++) {
    float4 z = matvec3(sregq, ldsS[g], Sb, yb, g, c);
    *(float4*)(zsc + g * NDIM + 4 * c) = z;
    __syncthreads();
    if (tid < 64) {
      float z8[8];
      combine_z(zsc, tid, z8);
      float ss = 0.f;
#pragma unroll
      for (int k = 0; k < 8; k++) ss += z8[k] * z8[k];
      ss = wave_sum64(ss);
      float inv = 1.0f / (sqrtf(ss) + 1e-12f);
#pragma unroll
      for (int k = 0; k < 8; k++) y8[k] = z8[k] * inv;
      store_y_pairs(yh2, tid, y8);
    }
    __syncthreads();
  }

  // ---- lambda_max, step ----
  float step = 0.f;
  {
    float4 z = matvec3(sregq, ldsS[g], Sb, yb, g, c);
    *(float4*)(zsc + g * NDIM + 4 * c) = z;
    __syncthreads();
    if (tid < 64) {
      float z8[8];
      combine_z(zsc, tid, z8);
      float dd = 0.f;
#pragma unroll
      for (int k = 0; k < 8; k++) dd += z8[k] * y8[k];
      dd = wave_sum64(dd);
      step = 1.0f / (2.0f * dd + 1e-8f);
    }
    __syncthreads();
  }

  // ---- FISTA ----
  float w8[8], mu8[8];
  if (tid < 64) {
#pragma unroll
    for (int k = 0; k < 8; k++) { w8[k] = invn; y8[k] = invn; }
    float4 m0 = ld4(mu + (size_t)b * NDIM + 8 * tid);
    float4 m1 = ld4(mu + (size_t)b * NDIM + 8 * tid + 4);
    mu8[0] = m0.x; mu8[1] = m0.y; mu8[2] = m0.z; mu8[3] = m0.w;
    mu8[4] = m1.x; mu8[5] = m1.y; mu8[6] = m1.z; mu8[7] = m1.w;
  }
  if (tid < NPAIR) { half2_t v; v[0] = (_Float16)invn; v[1] = (_Float16)invn; yh2[tid] = v; }
  __syncthreads();

  float t = 1.0f;
  int streak = 0;
  for (int it = 0; it < N_ITERS; it++) {
    float4 z = matvec3(sregq, ldsS[g], Sb, yb, g, c);
    *(float4*)(zsc + g * NDIM + 4 * c) = z;
    __syncthreads();
    if (tid < 64) {
      float z8[8], v8[8];
      combine_z(zsc, tid, z8);
#pragma unroll
      for (int k = 0; k < 8; k++)
        v8[k] = y8[k] - step * (2.0f * z8[k] - mu8[k]);

      // Michelot fixed-point simplex projection (exact)
      float th = -1e30f;
      for (int m = 0; m < 64; m++) {
        float s = 0.f, cn = 0.f;
#pragma unroll
        for (int k = 0; k < 8; k++)
          if (v8[k] > th) { s += v8[k]; cn += 1.f; }
#pragma unroll
        for (int off = 1; off < 64; off <<= 1) {
          s  += __shfl_xor(s, off, 64);
          cn += __shfl_xor(cn, off, 64);
        }
        float thn = (s - 1.0f) / cn;
        if (!(thn > th)) break;
        th = thn;
      }

      float tn = 0.5f * (1.0f + sqrtf(1.0f + 4.0f * t * t));
      float coef = (t - 1.0f) / tn;
      float maxinc = 0.f;
#pragma unroll
      for (int k = 0; k < 8; k++) {
        float wn = fmaxf(v8[k] - th, 0.0f);
        maxinc = fmaxf(maxinc, fabsf(wn - w8[k]));
        y8[k] = wn + coef * (wn - w8[k]);
        w8[k] = wn;
      }
      t = tn;
      store_y_pairs(yh2, tid, y8);
      maxinc = wave_max64(maxinc);
      streak = (maxinc < 1e-7f) ? streak + 1 : 0;
      if (tid == 0 && streak >= 3) stopf = 1;
    }
    __syncthreads();
    if (stopf) break;
  }

  if (tid < 64) {
    *(float4*)(out + (size_t)b * NDIM + 8 * tid)     = make_float4(w8[0], w8[1], w8[2], w8[3]);
    *(float4*)(out + (size_t)b * NDIM + 8 * tid + 4) = make_float4(w8[4], w8[5], w8[6], w8[7]);
  }
}

// ---------------- launch ----------------
extern "C" void kernel_launch(void* const* d_in, const int* in_sizes, int n_in,
                              void* d_out, int out_size, void* d_ws, size_t ws_size,
                              hipStream_t stream) {
  const float* mu = (const float*)d_in[0];
  const float* Sg = (const float*)d_in[1];
  if (n_in >= 2 && in_sizes[0] > in_sizes[1]) { mu = (const float*)d_in[1]; Sg = (const float*)d_in[0]; }
  float* out = (float*)d_out;

  half2_t* Sh = (half2_t*)d_ws;  // 64 MB (ws verified sufficient in round 2)
  sym_conv_kernel<<<dim3(BATCH, 16, 16), dim3(32, 8), 0, stream>>>(Sg, Sh);
  qp_solver_h<<<dim3(BATCH), dim3(512), 0, stream>>>(mu, Sh, out);
}

// Round 4
// 4364.248 us; speedup vs baseline: 1.2283x; 1.2283x over previous
//
#include <hip/hip_runtime.h>
#include <hip/hip_fp16.h>
#include <math.h>

#define BATCH 128
#define NDIM 512
#define NPAIR 256          // row-pairs per batch
#define POWER_ITERS 30
#define N_ITERS 500

// per-thread partition of its 64 owned row-pairs:
#define REGP 40            // pairs held in VGPRs (160 VGPRs)
#define LDSP 6             // pairs held in LDS (48 KB/block)
#define STRP 18            // pairs streamed from L2 each matvec (144 KB/block/iter)
#define SCH  6             // stream chunk (double-buffered: 2*24=48 VGPRs peak)

typedef _Float16 half2_t __attribute__((ext_vector_type(2)));

union H2x4 { float4 f4; half2_t h[4]; };

// ---------------- helpers ----------------
__device__ __forceinline__ float4 ld4(const float* p) { return *(const float4*)p; }
__device__ __forceinline__ float4 f4_add(float4 a, float4 b) {
  return make_float4(a.x + b.x, a.y + b.y, a.z + b.z, a.w + b.w);
}
__device__ __forceinline__ float wave_sum64(float x) {
#pragma unroll
  for (int off = 1; off < 64; off <<= 1) x += __shfl_xor(x, off, 64);
  return x;
}
__device__ __forceinline__ float wave_max64(float x) {
#pragma unroll
  for (int off = 1; off < 64; off <<= 1) x = fmaxf(x, __shfl_xor(x, off, 64));
  return x;
}

// ---- conversion: Sh[b][pair][col] = half2( sym(2p,col), sym(2p+1,col) ) ----
__global__ void sym_conv_kernel(const float* __restrict__ S, half2_t* __restrict__ Sh) {
  const int bb = blockIdx.x, ti = blockIdx.y, tj = blockIdx.z;
  if (tj < ti) return;
  __shared__ float ta[32][33];
  __shared__ float tb[32][33];
  const float* base = S + (size_t)bb * NDIM * NDIM;
  half2_t* dst = Sh + (size_t)bb * NPAIR * NDIM;
  const int tx = threadIdx.x, ty = threadIdx.y;  // 32 x 8
#pragma unroll
  for (int k = 0; k < 4; k++) {
    int r = ty + 8 * k;
    ta[r][tx] = base[(size_t)(ti * 32 + r) * NDIM + tj * 32 + tx];
    tb[r][tx] = base[(size_t)(tj * 32 + r) * NDIM + ti * 32 + tx];
  }
  __syncthreads();
#pragma unroll
  for (int k = 0; k < 2; k++) {
    int pi = ty + 8 * k;  // local pair 0..15
    float v0 = 0.5f * (ta[2 * pi][tx] + tb[tx][2 * pi]);
    float v1 = 0.5f * (ta[2 * pi + 1][tx] + tb[tx][2 * pi + 1]);
    half2_t o; o[0] = (_Float16)v0; o[1] = (_Float16)v1;
    dst[(size_t)(ti * 16 + pi) * NDIM + tj * 32 + tx] = o;
  }
  if (ti != tj) {
#pragma unroll
    for (int k = 0; k < 2; k++) {
      int pi = ty + 8 * k;
      float v0 = 0.5f * (tb[2 * pi][tx] + ta[tx][2 * pi]);
      float v1 = 0.5f * (tb[2 * pi + 1][tx] + ta[tx][2 * pi + 1]);
      half2_t o; o[0] = (_Float16)v0; o[1] = (_Float16)v1;
      dst[(size_t)(tj * 16 + pi) * NDIM + ti * 32 + tx] = o;
    }
  }
}

// ---- matvec partial over this thread's 64 pairs: regs + LDS + chunked L2 stream ----
__device__ __forceinline__ float4 matvec3(const float4 (&sregq)[REGP],
                                          const float4 (*ldsSg)[128],
                                          const half2_t* __restrict__ Sb,
                                          const half2_t* __restrict__ yb,
                                          int g, int c) {
  float a[2][4] = {{0, 0, 0, 0}, {0, 0, 0, 0}};
  const half2_t* gp = Sb + (size_t)(64 * g + REGP + LDSP) * NDIM + 4 * c;

  float4 stA[SCH], stB[SCH];
#pragma unroll
  for (int p = 0; p < SCH; p++) stA[p] = *(const float4*)(gp + (size_t)p * NDIM);

  // register part: pairs [0, REGP) — overlaps chunk-0 L2 latency
#pragma unroll
  for (int ch = 0; ch < REGP / 4; ch++) {
    H2x4 y4; y4.f4 = *(const float4*)(yb + 4 * ch);  // wave-uniform LDS broadcast
    float* ac = a[ch & 1];
#pragma unroll
    for (int q = 0; q < 4; q++) {
      H2x4 u; u.f4 = sregq[4 * ch + q];
      half2_t yy = y4.h[q];
      ac[0] = __builtin_amdgcn_fdot2(u.h[0], yy, ac[0], false);
      ac[1] = __builtin_amdgcn_fdot2(u.h[1], yy, ac[1], false);
      ac[2] = __builtin_amdgcn_fdot2(u.h[2], yy, ac[2], false);
      ac[3] = __builtin_amdgcn_fdot2(u.h[3], yy, ac[3], false);
    }
  }

#pragma unroll
  for (int p = 0; p < SCH; p++) stB[p] = *(const float4*)(gp + (size_t)(SCH + p) * NDIM);

  // LDS part: pairs [REGP, REGP+LDSP)
#pragma unroll
  for (int p = 0; p < LDSP; p++) {
    H2x4 u; u.f4 = ldsSg[p][c];
    half2_t yy = yb[REGP + p];
    float* ac = a[p & 1];
    ac[0] = __builtin_amdgcn_fdot2(u.h[0], yy, ac[0], false);
    ac[1] = __builtin_amdgcn_fdot2(u.h[1], yy, ac[1], false);
    ac[2] = __builtin_amdgcn_fdot2(u.h[2], yy, ac[2], false);
    ac[3] = __builtin_amdgcn_fdot2(u.h[3], yy, ac[3], false);
  }

  // streamed chunks with double-buffer: consume A, prefetch into A, consume B, ...
#pragma unroll
  for (int p = 0; p < SCH; p++) {  // consume chunk 0 (stA)
    H2x4 u; u.f4 = stA[p];
    half2_t yy = yb[REGP + LDSP + p];
    float* ac = a[p & 1];
    ac[0] = __builtin_amdgcn_fdot2(u.h[0], yy, ac[0], false);
    ac[1] = __builtin_amdgcn_fdot2(u.h[1], yy, ac[1], false);
    ac[2] = __builtin_amdgcn_fdot2(u.h[2], yy, ac[2], false);
    ac[3] = __builtin_amdgcn_fdot2(u.h[3], yy, ac[3], false);
  }
#pragma unroll
  for (int p = 0; p < SCH; p++) stA[p] = *(const float4*)(gp + (size_t)(2 * SCH + p) * NDIM);
#pragma unroll
  for (int p = 0; p < SCH; p++) {  // consume chunk 1 (stB)
    H2x4 u; u.f4 = stB[p];
    half2_t yy = yb[REGP + LDSP + SCH + p];
    float* ac = a[p & 1];
    ac[0] = __builtin_amdgcn_fdot2(u.h[0], yy, ac[0], false);
    ac[1] = __builtin_amdgcn_fdot2(u.h[1], yy, ac[1], false);
    ac[2] = __builtin_amdgcn_fdot2(u.h[2], yy, ac[2], false);
    ac[3] = __builtin_amdgcn_fdot2(u.h[3], yy, ac[3], false);
  }
#pragma unroll
  for (int p = 0; p < SCH; p++) {  // consume chunk 2 (stA)
    H2x4 u; u.f4 = stA[p];
    half2_t yy = yb[REGP + LDSP + 2 * SCH + p];
    float* ac = a[p & 1];
    ac[0] = __builtin_amdgcn_fdot2(u.h[0], yy, ac[0], false);
    ac[1] = __builtin_amdgcn_fdot2(u.h[1], yy, ac[1], false);
    ac[2] = __builtin_amdgcn_fdot2(u.h[2], yy, ac[2], false);
    ac[3] = __builtin_amdgcn_fdot2(u.h[3], yy, ac[3], false);
  }
  return make_float4(a[0][0] + a[1][0], a[0][1] + a[1][1],
                     a[0][2] + a[1][2], a[0][3] + a[1][3]);
}

__device__ __forceinline__ void combine_z(const float* __restrict__ zsc, int lane, float* z8) {
#pragma unroll
  for (int q = 0; q < 2; q++) {
    float4 zz = ld4(zsc + 0 * NDIM + 8 * lane + 4 * q);
    zz = f4_add(zz, ld4(zsc + 1 * NDIM + 8 * lane + 4 * q));
    zz = f4_add(zz, ld4(zsc + 2 * NDIM + 8 * lane + 4 * q));
    zz = f4_add(zz, ld4(zsc + 3 * NDIM + 8 * lane + 4 * q));
    z8[4 * q + 0] = zz.x; z8[4 * q + 1] = zz.y;
    z8[4 * q + 2] = zz.z; z8[4 * q + 3] = zz.w;
  }
}

__device__ __forceinline__ void store_y_pairs(half2_t* ysh, int lane, const float* y8) {
  H2x4 yo;
#pragma unroll
  for (int q = 0; q < 4; q++) {
    half2_t v; v[0] = (_Float16)y8[2 * q]; v[1] = (_Float16)y8[2 * q + 1];
    yo.h[q] = v;
  }
  *(float4*)(ysh + 4 * lane) = yo.f4;
}

__global__ void __launch_bounds__(512, 2)
qp_solver_h(const float* __restrict__ mu,
            const half2_t* __restrict__ Sh,
            float* __restrict__ out) {
  __shared__ half2_t yh2[NPAIR];            // 1 KB: y as fp16 row-pairs
  __shared__ float zsc[4 * NDIM];           // 8 KB: per-group matvec partials
  __shared__ float4 ldsS[4][LDSP][128];     // 48 KB: LDS-resident slab of S
  __shared__ int stopf;
  const int tid = threadIdx.x;
  const int g = tid >> 7;
  const int c = tid & 127;
  const int b = blockIdx.x;
  const half2_t* Sb = Sh + (size_t)b * NPAIR * NDIM;
  const half2_t* yb = yh2 + 64 * g;
  const float invn = 1.0f / (float)NDIM;

  // ---- stage: registers (pinned) + LDS slab ----
  float4 sregq[REGP];
  {
    const half2_t* rp = Sb + (size_t)(64 * g) * NDIM + 4 * c;
#pragma unroll
    for (int p = 0; p < REGP; p++)
      sregq[p] = *(const float4*)(rp + (size_t)p * NDIM);
#pragma unroll
    for (int p = 0; p < LDSP; p++)
      ldsS[g][p][c] = *(const float4*)(rp + (size_t)(REGP + p) * NDIM);
  }
  // make values opaque so LLVM can't re-load them from global inside the loop
#pragma unroll
  for (int p = 0; p < REGP; p++) {
    asm volatile("" : "+v"(sregq[p].x), "+v"(sregq[p].y),
                      "+v"(sregq[p].z), "+v"(sregq[p].w));
  }

  if (tid < NPAIR) { half2_t v; v[0] = (_Float16)invn; v[1] = (_Float16)invn; yh2[tid] = v; }
  if (tid == 0) stopf = 0;
  __syncthreads();

  float y8[8];  // wave0 only: current vector fp32
  // ---- power iteration ----
  for (int it = 0; it < POWER_ITERS; it++) {
    float4 z = matvec3(sregq, ldsS[g], Sb, yb, g, c);
    *(float4*)(zsc + g * NDIM + 4 * c) = z;
    __syncthreads();
    if (tid < 64) {
      float z8[8];
      combine_z(zsc, tid, z8);
      float ss = 0.f;
#pragma unroll
      for (int k = 0; k < 8; k++) ss += z8[k] * z8[k];
      ss = wave_sum64(ss);
      float inv = 1.0f / (sqrtf(ss) + 1e-12f);
#pragma unroll
      for (int k = 0; k < 8; k++) y8[k] = z8[k] * inv;
      store_y_pairs(yh2, tid, y8);
    }
    __syncthreads();
  }

  // ---- lambda_max, step ----
  float step = 0.f;
  {
    float4 z = matvec3(sregq, ldsS[g], Sb, yb, g, c);
    *(float4*)(zsc + g * NDIM + 4 * c) = z;
    __syncthreads();
    if (tid < 64) {
      float z8[8];
      combine_z(zsc, tid, z8);
      float dd = 0.f;
#pragma unroll
      for (int k = 0; k < 8; k++) dd += z8[k] * y8[k];
      dd = wave_sum64(dd);
      step = 1.0f / (2.0f * dd + 1e-8f);
    }
    __syncthreads();
  }

  // ---- FISTA ----
  float w8[8], mu8[8];
  if (tid < 64) {
#pragma unroll
    for (int k = 0; k < 8; k++) { w8[k] = invn; y8[k] = invn; }
    float4 m0 = ld4(mu + (size_t)b * NDIM + 8 * tid);
    float4 m1 = ld4(mu + (size_t)b * NDIM + 8 * tid + 4);
    mu8[0] = m0.x; mu8[1] = m0.y; mu8[2] = m0.z; mu8[3] = m0.w;
    mu8[4] = m1.x; mu8[5] = m1.y; mu8[6] = m1.z; mu8[7] = m1.w;
  }
  if (tid < NPAIR) { half2_t v; v[0] = (_Float16)invn; v[1] = (_Float16)invn; yh2[tid] = v; }
  __syncthreads();

  float t = 1.0f;
  int streak = 0;
  for (int it = 0; it < N_ITERS; it++) {
    float4 z = matvec3(sregq, ldsS[g], Sb, yb, g, c);
    *(float4*)(zsc + g * NDIM + 4 * c) = z;
    __syncthreads();
    if (tid < 64) {
      float z8[8], v8[8];
      combine_z(zsc, tid, z8);
#pragma unroll
      for (int k = 0; k < 8; k++)
        v8[k] = y8[k] - step * (2.0f * z8[k] - mu8[k]);

      // Michelot fixed-point simplex projection (exact)
      float th = -1e30f;
      for (int m = 0; m < 64; m++) {
        float s = 0.f, cn = 0.f;
#pragma unroll
        for (int k = 0; k < 8; k++)
          if (v8[k] > th) { s += v8[k]; cn += 1.f; }
#pragma unroll
        for (int off = 1; off < 64; off <<= 1) {
          s  += __shfl_xor(s, off, 64);
          cn += __shfl_xor(cn, off, 64);
        }
        float thn = (s - 1.0f) / cn;
        if (!(thn > th)) break;
        th = thn;
      }

      float tn = 0.5f * (1.0f + sqrtf(1.0f + 4.0f * t * t));
      float coef = (t - 1.0f) / tn;
      float maxinc = 0.f;
#pragma unroll
      for (int k = 0; k < 8; k++) {
        float wn = fmaxf(v8[k] - th, 0.0f);
        maxinc = fmaxf(maxinc, fabsf(wn - w8[k]));
        y8[k] = wn + coef * (wn - w8[k]);
        w8[k] = wn;
      }
      t = tn;
      store_y_pairs(yh2, tid, y8);
      maxinc = wave_max64(maxinc);
      streak = (maxinc < 1e-7f) ? streak + 1 : 0;
      if (tid == 0 && streak >= 3) stopf = 1;
    }
    __syncthreads();
    if (stopf) break;
  }

  if (tid < 64) {
    *(float4*)(out + (size_t)b * NDIM + 8 * tid)     = make_float4(w8[0], w8[1], w8[2], w8[3]);
    *(float4*)(out + (size_t)b * NDIM + 8 * tid + 4) = make_float4(w8[4], w8[5], w8[6], w8[7]);
  }
}

// ---------------- launch ----------------
extern "C" void kernel_launch(void* const* d_in, const int* in_sizes, int n_in,
                              void* d_out, int out_size, void* d_ws, size_t ws_size,
                              hipStream_t stream) {
  const float* mu = (const float*)d_in[0];
  const float* Sg = (const float*)d_in[1];
  if (n_in >= 2 && in_sizes[0] > in_sizes[1]) { mu = (const float*)d_in[1]; Sg = (const float*)d_in[0]; }
  float* out = (float*)d_out;

  half2_t* Sh = (half2_t*)d_ws;  // 64 MB (ws verified sufficient in round 2)
  sym_conv_kernel<<<dim3(BATCH, 16, 16), dim3(32, 8), 0, stream>>>(Sg, Sh);
  qp_solver_h<<<dim3(BATCH), dim3(512), 0, stream>>>(mu, Sh, out);
}